// Round 5
// baseline (159.819 us; speedup 1.0000x reference)
//
#include <hip/hip_runtime.h>

// Problem constants (fixed by setup_inputs)
static constexpr int B_ = 256;
static constexpr int T_ = 16384;
static constexpr int TPB = 1024;                 // threads per block (16 waves)
static constexpr int F4_ROW = T_ * 2 / 4;        // 8192 float4 per b-row
static constexpr int CHUNKS = F4_ROW / TPB;      // 8 chunks per row

static constexpr float DTc    = 0.01f;
static constexpr float MINVAR = 0.01f;
static constexpr float EPSc   = 1e-6f;

// ws layout: float pPos[256], pLve[256], pLc[256], pReg[256]  (4 KB total)

__device__ __forceinline__ float waveReduce(float v) {
#pragma unroll
  for (int d = 32; d > 0; d >>= 1) v += __shfl_down(v, d, 64);
  return v;
}
__device__ __forceinline__ double waveReduceD(double v) {
#pragma unroll
  for (int d = 32; d > 0; d >>= 1) v += __shfl_down(v, d, 64);
  return v;
}

// One block per batch row. Single pass over vel/cov/vgt/pgt.
// Scan: per-chunk wave shuffle-scan + cross-wave LDS combine, running offset in regs.
__global__ __launch_bounds__(TPB) void fusedKern(
    const float4* __restrict__ vel, const float4* __restrict__ cov,
    const float4* __restrict__ vgt, const float4* __restrict__ pgt,
    float* __restrict__ pPos, float* __restrict__ pLve,
    float* __restrict__ pLc,  float* __restrict__ pReg) {
  const int b = blockIdx.x;
  const int tid = threadIdx.x;
  const int lane = tid & 63, wid = tid >> 6;       // 16 waves
  const int rowbase = b * F4_ROW;

  __shared__ float2 wt[2][16];                     // per-wave chunk totals, double-buffered
  __shared__ float  sh[4][16];                     // final stats combine

  const float2 v0 = ((const float2*)vel)[b * T_];  // broadcast read (same addr all lanes)

  float runx = 0.f, runy = 0.f;                    // prefix of previous chunks
  float lve = 0.f, lc = 0.f, reg = 0.f, apos = 0.f;

  // preload chunk 0
  float4 v = vel[rowbase + tid];
  float4 c = cov[rowbase + tid];
  float4 g = vgt[rowbase + tid];
  float4 p = pgt[rowbase + tid];

  for (int ch = 0; ch < CHUNKS; ++ch) {
    // issue next chunk's loads early — they overlap this chunk's scan/compute
    float4 nv, nc, ng, np;
    const bool more = (ch + 1 < CHUNKS);
    if (more) {
      int idx = rowbase + (ch + 1) * TPB + tid;
      nv = vel[idx]; nc = cov[idx]; ng = vgt[idx]; np = pgt[idx];
    }

    // ---- elementwise stats (no sync needed) ----
    {
      float dx = g.x - v.x, dy = g.y - v.y;
      float sqx = dx * dx, sqy = dy * dy;
      lve += sqx + sqy;
      float sx = fmaxf(__expf(c.x), MINVAR);
      float sy = fmaxf(__expf(c.y), MINVAR);
      float ixv = 1.0f / sx, iyv = 1.0f / sy;
      lc += ixv * sqx + iyv * sqy + __logf(sx * sy + EPSc);
      reg += ixv + iyv;
    }
    {
      float dx = g.z - v.z, dy = g.w - v.w;
      float sqx = dx * dx, sqy = dy * dy;
      lve += sqx + sqy;
      float sx = fmaxf(__expf(c.z), MINVAR);
      float sy = fmaxf(__expf(c.w), MINVAR);
      float ixv = 1.0f / sx, iyv = 1.0f / sy;
      lc += ixv * sqx + iyv * sqy + __logf(sx * sy + EPSc);
      reg += ixv + iyv;
    }

    // ---- scan of vel float4-sums (each float4 = timesteps 2f, 2f+1) ----
    const float sx = v.x + v.z, sy = v.y + v.w;    // this thread's float4 sum
    float ix = sx, iy = sy;                        // wave inclusive scan
#pragma unroll
    for (int d = 1; d < 64; d <<= 1) {
      float ux = __shfl_up(ix, (unsigned)d, 64);
      float uy = __shfl_up(iy, (unsigned)d, 64);
      if (lane >= d) { ix += ux; iy += uy; }
    }
    const int slot = ch & 1;
    if (lane == 63) wt[slot][wid] = make_float2(ix, iy);
    __syncthreads();                               // one barrier per chunk (dbuf'd wt)

    float offx = ix - sx + runx, offy = iy - sy + runy;  // exclusive prefix for this float4
    float ctx = 0.f, cty = 0.f;                    // chunk total
#pragma unroll
    for (int w = 0; w < 16; ++w) {
      float2 t = wt[slot][w];
      if (w < wid) { offx += t.x; offy += t.y; }
      ctx += t.x; cty += t.y;
    }

    // ---- position MSE: pos[t] = DT*(v0 + prefix(t)) ----
    {
      float px = DTc * (v0.x + offx), py = DTc * (v0.y + offy);
      float ex = px - p.x, ey = py - p.y;
      apos += ex * ex + ey * ey;
      float bx2 = offx + v.x, by2 = offy + v.y;
      px = DTc * (v0.x + bx2); py = DTc * (v0.y + by2);
      ex = px - p.z; ey = py - p.w;
      apos += ex * ex + ey * ey;
    }

    runx += ctx; runy += cty;
    if (more) { v = nv; c = nc; g = ng; p = np; }
  }

  // ---- block reduce the 4 stats ----
  float r0 = waveReduce(apos);
  float r1 = waveReduce(lve);
  float r2 = waveReduce(lc);
  float r3 = waveReduce(reg);
  __syncthreads();                                 // wt reuse safety before sh writes? separate arrays, but order anyway
  if (lane == 0) { sh[0][wid] = r0; sh[1][wid] = r1; sh[2][wid] = r2; sh[3][wid] = r3; }
  __syncthreads();
  if (tid == 0) {
    float t0 = 0.f, t1 = 0.f, t2 = 0.f, t3 = 0.f;
#pragma unroll
    for (int w = 0; w < 16; ++w) { t0 += sh[0][w]; t1 += sh[1][w]; t2 += sh[2][w]; t3 += sh[3][w]; }
    pPos[b] = t0; pLve[b] = t1; pLc[b] = t2; pReg[b] = t3;
  }
}

__global__ __launch_bounds__(256) void kernC(
    const float* __restrict__ pPos, const float* __restrict__ pLve,
    const float* __restrict__ pLc,  const float* __restrict__ pReg,
    const float* __restrict__ pldv, const float* __restrict__ pldc,
    float* __restrict__ out) {
  const int tid = threadIdx.x;
  const int lane = tid & 63, wid = tid >> 6;
  double a0 = (double)pPos[tid];
  double a1 = (double)pLve[tid];
  double a2 = (double)pLc[tid];
  double a3 = (double)pReg[tid];
  a0 = waveReduceD(a0);
  a1 = waveReduceD(a1);
  a2 = waveReduceD(a2);
  a3 = waveReduceD(a3);
  __shared__ double sh[4][4];
  if (lane == 0) { sh[0][wid] = a0; sh[1][wid] = a1; sh[2][wid] = a2; sh[3][wid] = a3; }
  __syncthreads();
  if (tid == 0) {
    double pos_sq = sh[0][0] + sh[0][1] + sh[0][2] + sh[0][3];
    double vel_sq = sh[1][0] + sh[1][1] + sh[1][2] + sh[1][3];
    double lcs    = sh[2][0] + sh[2][1] + sh[2][2] + sh[2][3];
    double regs   = sh[3][0] + sh[3][1] + sh[3][2] + sh[3][3];
    const double NBT2 = (double)B_ * (double)T_ * 2.0;
    const double NBT  = (double)B_ * (double)T_;
    double lv  = (pos_sq + vel_sq) / NBT2;
    double lc  = 0.5 * lcs / NBT;
    double reg = regs / NBT;
    double ldv = (double)pldv[0], ldc = (double)pldc[0];
    double total = lv / (2.0 * exp(2.0 * ldv)) + lc / (2.0 * exp(2.0 * ldc))
                 + ldv + ldc + 0.01 * reg;
    out[0] = (float)total;
  }
}

extern "C" void kernel_launch(void* const* d_in, const int* in_sizes, int n_in,
                              void* d_out, int out_size, void* d_ws, size_t ws_size,
                              hipStream_t stream) {
  const float4* vel = (const float4*)d_in[0];
  const float4* cov = (const float4*)d_in[1];
  const float4* vgt = (const float4*)d_in[2];
  const float4* pgt = (const float4*)d_in[3];
  const float* ldv = (const float*)d_in[4];
  const float* ldc = (const float*)d_in[5];

  char* ws = (char*)d_ws;
  float* pPos = (float*)ws;                 // 1 KB
  float* pLve = (float*)(ws + 1024);        // 1 KB
  float* pLc  = (float*)(ws + 2048);        // 1 KB
  float* pReg = (float*)(ws + 3072);        // 1 KB

  fusedKern<<<B_, TPB, 0, stream>>>(vel, cov, vgt, pgt, pPos, pLve, pLc, pReg);
  kernC<<<1, 256, 0, stream>>>(pPos, pLve, pLc, pReg, ldv, ldc, (float*)d_out);
}